// Round 18
// baseline (233.031 us; speedup 1.0000x reference)
//
#include <hip/hip_runtime.h>
#include <hip/hip_bf16.h>
#include <hip/hip_fp16.h>

#define HW 16384   // 128*128

typedef unsigned short u16;
typedef unsigned int   u32;
typedef __attribute__((ext_vector_type(8))) short short8v;
typedef __attribute__((ext_vector_type(8))) _Float16 half8v;
typedef __attribute__((ext_vector_type(2))) __fp16 fp16x2;
typedef __attribute__((ext_vector_type(4))) float float4v;

__device__ __forceinline__ float b2f(u16 v) { return __uint_as_float((u32)v << 16); }
__device__ __forceinline__ u16 f2bf(float f) {   // RNE (cold paths)
  u32 u = __float_as_uint(f);
  u32 r = (u + 0x7fffu + ((u >> 16) & 1u)) >> 16;
  return (u16)r;
}
__device__ __forceinline__ u16 f2h(float f) {    // f32 -> f16 RNE (cold paths)
  _Float16 h = (_Float16)f;
  return *(u16*)&h;
}
__device__ __forceinline__ float bflo(u32 u) { return __uint_as_float(u << 16); }
__device__ __forceinline__ float bfhi(u32 u) { return __uint_as_float(u & 0xffff0000u); }
// 1-instruction truncating pack: (hi16(b)<<16)|hi16(a)  [v_perm_b32]
__device__ __forceinline__ u32 pkt(float a, float b) {
  return __builtin_amdgcn_perm(__float_as_uint(b), __float_as_uint(a), 0x07060302u);
}
__device__ __forceinline__ u16 bft(float v) { return (u16)(__float_as_uint(v) >> 16); }  // trunc
// f32 pair -> packed f16 pair (v_cvt_pkrtz_f16_f32, 1 op); builtin-native type
__device__ __forceinline__ u32 pkh(float a, float b) {
  union { fp16x2 h; u32 u; } cv;
  cv.h = __builtin_amdgcn_cvt_pkrtz(a, b);
  return cv.u;
}

// ---------------------------------------------------------------------------
// K0: swizzle ALL weights into MFMA-B fragment order.
//  wTb/woffb F16 (DCN path); wB1/w3b BF16.
// ---------------------------------------------------------------------------
__global__ __launch_bounds__(256) void k_init(const float* __restrict__ w_dc,
                                              const float* __restrict__ w1,
                                              const float* __restrict__ w_ds,
                                              const float* __restrict__ w3,
                                              const float* __restrict__ w_off,
                                              u16* __restrict__ wTb, u16* __restrict__ wB1,
                                              u16* __restrict__ w3b, u16* __restrict__ woffb) {
  int idx = blockIdx.x * 256 + threadIdx.x;
  if (idx < 147456) {
    int ntile = idx / 18432, r = idx % 18432;
    int ks = r / 512, r2 = r % 512;
    int lane = r2 / 8, j = r2 % 8;
    int o = ntile * 16 + (lane & 15);
    int k = ks * 32 + ((lane >> 4) * 8) + j;
    int tap = k >> 7, ci = k & 127;
    wTb[idx] = f2h(w_dc[(o * 128 + ci) * 9 + tap]);           // f16
  }
  int i1 = idx - 147456;
  if (i1 >= 0 && i1 < 65536) {
    int ntile = i1 / 4096, r = i1 % 4096;
    int ks = r / 512, r2 = r % 512;
    int lane = r2 / 8, j = r2 % 8;
    int o = ntile * 16 + (lane & 15);
    int c = ks * 32 + ((lane >> 4) * 8) + j;
    float v = (ntile < 8) ? w1[o * 256 + c] : w_ds[(o - 128) * 256 + c];
    wB1[i1] = f2bf(v);                                        // bf16
  }
  int i2 = idx - 212992;
  if (i2 >= 0 && i2 < 16384) {
    int ntile = i2 / 2048, r = i2 % 2048;
    int ks = r / 512, r2 = r % 512;
    int lane = r2 / 8, j = r2 % 8;
    int o = ntile * 16 + (lane & 15);
    int c = ks * 32 + ((lane >> 4) * 8) + j;
    w3b[i2] = f2bf(w3[o * 128 + c]);                          // bf16
  }
  int i3 = idx - 229376;
  if (i3 >= 0 && i3 < 36864) {
    int ntile = i3 / 18432, r = i3 % 18432;
    int ks = r / 512, r2 = r % 512;
    int lane = r2 / 8, j = r2 % 8;
    int oc = ntile * 16 + (lane & 15);
    int k = ks * 32 + ((lane >> 4) * 8) + j;
    int tap = k >> 7, c = k & 127;
    woffb[i3] = (oc < 27) ? f2h(w_off[oc * 1152 + c * 9 + tap]) : (u16)0;   // f16
  }
}

// ---------------------------------------------------------------------------
// K1 v4: fused conv1+downsample MFMA GEMM. M=32, N=256, K=256.
//  (proven; unchanged) grid (4,128,4); block 256 = 4 waves.
// ---------------------------------------------------------------------------
__global__ __launch_bounds__(256) void k_fused1(const float* __restrict__ x,
                                                const u16* __restrict__ wB1,
                                                const float* __restrict__ s1a, const float* __restrict__ t1a,
                                                const float* __restrict__ s1b, const float* __restrict__ t1b,
                                                const float* __restrict__ b_ds,
                                                const float* __restrict__ sd, const float* __restrict__ td,
                                                u16* __restrict__ out1,      // [b][h][w][o]  F16
                                                u16* __restrict__ identb)    // [b][o][h][w]  BF16
{
  __shared__ __align__(16) u16 xA[8704];
  const int tid = threadIdx.x;
  const int wq = blockIdx.x, h = blockIdx.y, b = blockIdx.z;
  const int wave = tid >> 6, lane = tid & 63;

  {
    const float* xb = x + (size_t)b * 256 * HW + h * 128 + wq * 32;
    u32* dst = (u32*)xA;                 // u32 pitch 133 per pos row
    int cp = tid >> 3, wg = tid & 7;
#pragma unroll
    for (int i = 0; i < 4; ++i) {
      int cpair = i * 32 + cp;           // 0..127
      int c0 = cpair * 2;
      float4 va = *(const float4*)&xb[(size_t)c0 * HW + wg * 4];
      float4 vb = *(const float4*)&xb[(size_t)(c0 + 1) * HW + wg * 4];
      int p0 = wg * 4;
      dst[(p0 + 0) * 133 + cpair] = pkt(va.x, vb.x);
      dst[(p0 + 1) * 133 + cpair] = pkt(va.y, vb.y);
      dst[(p0 + 2) * 133 + cpair] = pkt(va.z, vb.z);
      dst[(p0 + 3) * 133 + cpair] = pkt(va.w, vb.w);
    }
  }
  __syncthreads();

  const int nlo = lane & 15, kgr = lane >> 4;
  float4v acc[2][4];
#pragma unroll
  for (int mt = 0; mt < 2; ++mt)
#pragma unroll
    for (int nt = 0; nt < 4; ++nt) acc[mt][nt] = (float4v)(0.f);

  const u16* a0p = &xA[nlo * 266 + kgr * 8];
  const u16* a1p = &xA[(nlo + 16) * 266 + kgr * 8];
  const u16* bp = &wB1[(((size_t)(wave * 4) * 8) * 64 + lane) * 8];

#pragma unroll
  for (int ks = 0; ks < 8; ++ks) {
    short8v a0 = *(const short8v*)(a0p + ks * 32);
    short8v a1 = *(const short8v*)(a1p + ks * 32);
#pragma unroll
    for (int nt = 0; nt < 4; ++nt) {
      short8v bv = *(const short8v*)(bp + nt * 4096 + ks * 512);
      acc[0][nt] = __builtin_amdgcn_mfma_f32_16x16x32_bf16(a0, bv, acc[0][nt], 0, 0, 0);
      acc[1][nt] = __builtin_amdgcn_mfma_f32_16x16x32_bf16(a1, bv, acc[1][nt], 0, 0, 0);
    }
  }
  __syncthreads();   // xA dead; reuse as P1 + T1

  u16* P1 = xA;              // [pos][136]  (f16 out1 tile)
  u16* T1 = xA + 4352;       // [o][34]     (bf16 ident tile)

  const int rbase = kgr * 4;
  if (wave < 2) {
#pragma unroll
    for (int nt = 0; nt < 4; ++nt) {
      int o = (wave * 4 + nt) * 16 + nlo;
      float sa = s1a[o], ta = t1a[o], sb = s1b[o], tb = t1b[o];
#pragma unroll
      for (int mt = 0; mt < 2; ++mt)
#pragma unroll
        for (int r = 0; r < 4; ++r) {
          float v = acc[mt][nt][r];
          v = fmaxf(sa * v + ta, 0.f);
          v = fmaxf(sb * v + tb, 0.f);
          int pos = mt * 16 + rbase + r;
          P1[pos * 136 + o] = f2h(v);                  // F16
        }
    }
  } else {
#pragma unroll
    for (int nt = 0; nt < 4; ++nt) {
      int og = (wave * 4 + nt) * 16 + nlo - 128;
      float sv = sd[og], tv = td[og], bv = b_ds[og];
#pragma unroll
      for (int mt = 0; mt < 2; ++mt)
#pragma unroll
        for (int r = 0; r < 4; ++r) {
          float v = sv * (acc[mt][nt][r] + bv) + tv;
          T1[og * 34 + mt * 16 + rbase + r] = bft(v);  // BF16
        }
    }
  }
  __syncthreads();

  // ---- out1: fully-coalesced uint4 stores (f16 payload) ----
  {
    size_t rowbase = ((size_t)((b * 128 + h) * 128 + wq * 32)) * 128;
#pragma unroll
    for (int i = 0; i < 2; ++i) {
      int s = i * 256 + tid;             // 0..511
      int pos = s >> 4, q = s & 15;
      uint4 v = *(const uint4*)&P1[pos * 136 + q * 8];
      *(uint4*)&out1[rowbase + (size_t)pos * 128 + q * 8] = v;
    }
  }
  // ---- identb: transpose store (bf16, unchanged) ----
  {
    int o = tid >> 1, half = tid & 1;
    const u16* src = &T1[o * 34 + half * 16];
    u32 bb[8];
#pragma unroll
    for (int i = 0; i < 8; ++i) bb[i] = *(const u32*)(src + i * 2);
    size_t g = ((size_t)((b * 128 + o) * 128 + h)) * 128 + wq * 32 + half * 16;
    *(uint4*)&identb[g] = make_uint4(bb[0], bb[1], bb[2], bb[3]);
    *(uint4*)&identb[g + 8] = make_uint4(bb[4], bb[5], bb[6], bb[7]);
  }
}

// ---------------------------------------------------------------------------
// K2: MEGA-FUSED DCNv2, v15 = v14 scaled to an M=128 TILE (8 rows x 16 cols):
//  each wave's 72 wTb B-fragment loads feed FOUR m-sub-tiles (1 load -> 4
//  MFMAs); per-CU sequential blocks drop 4->2, halving per-output weight
//  TA traffic again. 1 block/CU (LDS 102.1 KB) — testing the session
//  finding that per-output traffic, not occupancy, governs time.
//  A2: ntile(2) x mtgroup(4), 2 mtiles/wave, full K. A3: 3-iter job loop,
//  compute -> barrier -> write Jl (overlays offp). Loop B: ks(4) x mh(2),
//  4 m-subs share B-frags, barrier-free. Reduction: 4 stages x 32 pos
//  (Pp 64 KB in dead W). conv3 M=128 (acc2[8]).
//  grid (8,16,4)=512; block 512; __launch_bounds__(512,2).
// ---------------------------------------------------------------------------
__global__ __launch_bounds__(512, 2) void k_dcn(const u16* __restrict__ out1,
                                                const u16* __restrict__ wTb,
                                                const u16* __restrict__ w3b,
                                                const u16* __restrict__ woffb,
                                                const float* __restrict__ b_off,
                                                const float* __restrict__ b_dc,
                                                const float* __restrict__ s2, const float* __restrict__ t2,
                                                const float* __restrict__ s3a, const float* __restrict__ t3a,
                                                const float* __restrict__ s3b, const float* __restrict__ t3b,
                                                const u16* __restrict__ identb,
                                                float* __restrict__ out) {
  // LDS map (102,144 B):
  //  W    [0, 65280)       : 240 px x 136 u16 (12x20 window, f16)
  //  reg2 [65280, 102144)  : offp 128x32 f32 (16 KB) THEN Jl 1152x8 u32 (36,864)
  //  reduce (W dead): P [0,34816) 128x136 u16 ; Pp [34816,100352) 16384 f32
  //  conv3/epilogue : P + T2 [34816,100864) 128x129 f32 (Pp dead)
  __shared__ __align__(16) u16 U[51072];

  u16*   W    = U;                                  // pitch 136 u16
  float* offp = (float*)((char*)U + 65280);         // [pos128][oc32]
  u32*   Jl   = (u32*)((char*)U + 65280);           // jobtab (overlays offp)
  float* Pp   = (float*)((char*)U + 34816);         // [ks][p32][o128]
  u16*   P    = U;                                  // [pos128][136]
  float* T2   = (float*)((char*)U + 34816);         // [o][129]

  const int tid = threadIdx.x;
  // XCD-chunked bijective swizzle (512 blocks, 8 XCDs, 512%8==0)
  const int flat = blockIdx.x + (blockIdx.y << 3) + (blockIdx.z << 7);
  const int nid = (flat & 7) * 64 + (flat >> 3);
  const int wq = nid & 7, th = (nid >> 3) & 15, b = nid >> 7;
  const int h0 = th * 8, w0 = wq * 16;   // tile rows h0..h0+7, cols w0..w0+15
  const int wave = tid >> 6, lane = tid & 63;
  const int nlo = lane & 15, kgr = lane >> 4;
  const u16* base = out1 + (size_t)b * HW * 128;

  // ---- A1: stage 12x20x128 window rows h0-2..h0+9, cols w0-2..w0+17 ----
  for (int k = tid; k < 3840; k += 512) {           // 240 px * 16 quads
    int pix = k >> 4, q = k & 15;
    int ri = pix / 20, ci = pix % 20;
    int y = h0 - 2 + ri, x = w0 - 2 + ci;
    uint4 g = make_uint4(0u, 0u, 0u, 0u);
    if ((y >= 0) & (y < 128) & (x >= 0) & (x < 128))
      g = *(const uint4*)&base[((size_t)(y * 128 + x)) * 128 + q * 8];
    *(uint4*)&W[pix * 136 + q * 8] = g;
  }
  __syncthreads();

  // ---- A2: offset conv (f16), waves = ntile(2) x mtgroup(4), 2 mt each ----
  // pos (pr=mt, pc=nlo): image (h0+mt-1+ty, w0+nlo-1+tx)
  //   -> W entry (mt+ty+1)*20 + nlo+tx+1   (mt 0..7, ri <= 10 < 12)
  {
    const int ntile = wave & 1, mtg = wave >> 1;    // mtg 0..3
    float4v oacc[2];
    oacc[0] = (float4v)(0.f); oacc[1] = (float4v)(0.f);
    for (int t = 0; t < 9; ++t) {
      int ty = t / 3, tx = t % 3;
      const u16* bp = &woffb[(((size_t)(ntile * 36 + t * 4)) * 64 + lane) * 8];
#pragma unroll
      for (int ksl = 0; ksl < 4; ++ksl) {
        half8v bv = *(const half8v*)(bp + ksl * 512);
#pragma unroll
        for (int sub = 0; sub < 2; ++sub) {
          int mt = mtg * 2 + sub;
          const u16* ap = &W[((mt + ty + 1) * 20 + nlo + tx + 1) * 136 + ksl * 32 + kgr * 8];
          half8v a = *(const half8v*)ap;
          oacc[sub] = __builtin_amdgcn_mfma_f32_16x16x32_f16(a, bv, oacc[sub], 0, 0, 0);
        }
      }
    }
    int oc = ntile * 16 + nlo;
#pragma unroll
    for (int sub = 0; sub < 2; ++sub)
#pragma unroll
      for (int r = 0; r < 4; ++r)
        offp[((mtg * 2 + sub) * 16 + kgr * 4 + r) * 32 + oc] = oacc[sub][r];
  }
  __syncthreads();

  // ---- A3: 1152 jobs; compute (reads offp) -> barrier -> write Jl ----
  u32  jc[3][4];
  float jw[3][4];
#pragma unroll
  for (int it = 0; it < 3; ++it) {
    int j = tid + it * 512;
    if (j < 1152) {
      int pos = j / 9, tap = j % 9;
      int pr = pos >> 4, pc = pos & 15;
      int hh = h0 + pr, w = w0 + pc;
      float dy  = offp[pos * 32 + tap]      + b_off[tap];
      float dxv = offp[pos * 32 + 9 + tap]  + b_off[9 + tap];
      float sg  = offp[pos * 32 + 18 + tap] + b_off[18 + tap];
      float mk = 1.f / (1.f + __expf(-sg));
      float py = (float)(hh - 1 + tap / 3) + dy;
      float px = (float)(w - 1 + tap % 3) + dxv;
      float fy = floorf(py), fx = floorf(px);
      int y0 = (int)fy, x0 = (int)fx;
      float wy = py - fy, wxf = px - fx;
      bool vy0 = (y0 >= 0) & (y0 < 128), vy1 = (y0 >= -1) & (y0 < 127);
      bool vx0 = (x0 >= 0) & (x0 < 128), vx1 = (x0 >= -1) & (x0 < 127);
      jw[it][0] = (vy0 & vx0) ? (1.f - wy) * (1.f - wxf) * mk : 0.f;
      jw[it][1] = (vy0 & vx1) ? (1.f - wy) * wxf * mk : 0.f;
      jw[it][2] = (vy1 & vx0) ? wy * (1.f - wxf) * mk : 0.f;
      jw[it][3] = (vy1 & vx1) ? wy * wxf * mk : 0.f;
      int y0c = min(max(y0, 0), 127), y1c = min(max(y0 + 1, 0), 127);
      int x0c = min(max(x0, 0), 127), x1c = min(max(x0 + 1, 0), 127);
      auto enc = [&](int yc, int xc) -> u32 {
        int ri = yc - (h0 - 2), ci = xc - (w0 - 2);
        if (((unsigned)ri < 12u) && ((unsigned)ci < 20u))
          return 0x80000000u | (u32)((ri * 20 + ci) * 136);
        return (u32)((yc * 128 + xc) * 128);
      };
      jc[it][0] = enc(y0c, x0c);
      jc[it][1] = enc(y0c, x1c);
      jc[it][2] = enc(y1c, x0c);
      jc[it][3] = enc(y1c, x1c);
    }
  }
  __syncthreads();           // offp reads complete; Jl may overwrite
#pragma unroll
  for (int it = 0; it < 3; ++it) {
    int j = tid + it * 512;
    if (j < 1152) {
      u32* jt = &Jl[j * 8];
      jt[0] = jc[it][0]; jt[1] = jc[it][1]; jt[2] = jc[it][2]; jt[3] = jc[it][3];
      ((float*)jt)[4] = jw[it][0]; ((float*)jt)[5] = jw[it][1];
      ((float*)jt)[6] = jw[it][2]; ((float*)jt)[7] = jw[it][3];
    }
  }
  __syncthreads();

  // ---- Loop B: DCN conv (f16), ks(4) x mh(2), 4 m-subs share B-frags ----
  float4v acc8[4][8];
#pragma unroll
  for (int ms = 0; ms < 4; ++ms)
#pragma unroll
    for (int nt = 0; nt < 8; ++nt) acc8[ms][nt] = (float4v)(0.f);
  {
    const int ks = wave & 3, mh = wave >> 2;
    const int ch0 = ks * 32 + kgr * 8;

    auto BLD = [&](int jidx) -> half8v {
      const u32* jt = &Jl[jidx * 8];
      uint4 co4 = *(const uint4*)jt;
      float4 w4 = *(const float4*)(jt + 4);
      u32 cos[4] = {co4.x, co4.y, co4.z, co4.w};
      float wf[4] = {w4.x, w4.y, w4.z, w4.w};
      float alo[4] = {0.f, 0.f, 0.f, 0.f};
      float ahi[4] = {0.f, 0.f, 0.f, 0.f};
#pragma unroll
      for (int c = 0; c < 4; ++c) {
        u32 co = cos[c];
        short8v cv;
        if (co & 0x80000000u)
          cv = *(const short8v*)&W[(co & 0x7fffffffu) + ch0];   // LDS pipe
        else
          cv = *(const short8v*)(base + co + ch0);              // rare global
        union { short8v s; _Float16 h[8]; } cc; cc.s = cv;
        float wk = wf[c];
#pragma unroll
        for (int p = 0; p < 4; ++p) {
          alo[p] = fmaf(wk, (float)cc.h[2 * p],     alo[p]);
          ahi[p] = fmaf(wk, (float)cc.h[2 * p + 1], ahi[p]);
        }
      }
      union { u32 u[4]; half8v s; } av;
#pragma unroll
      for (int p = 0; p < 4; ++p) av.u[p] = pkh(alo[p], ahi[p]);
      return av.s;
    };

#pragma unroll
    for (int t = 0; t < 9; ++t) {
      half8v av0 = BLD(((mh * 64 +  0) + nlo) * 9 + t);
      half8v av1 = BLD(((mh * 64 + 16) + nlo) * 9 + t);
      half8v av2 = BLD(((mh * 64 + 32) + nlo) * 9 + t);
      half8v av3 = BLD(((mh * 64 + 48) + nlo) * 9 + t);
      const u16* bb = &wTb[(((size_t)(t * 4 + ks)) * 64 + lane) * 8];
      __builtin_amdgcn_s_setprio(1);
#pragma unroll
      for (int nt = 0; nt < 8; ++nt) {
        half8v bv = *(const half8v*)(bb + (size_t)nt * 18432);
        acc8[0][nt] = __builtin_amdgcn_mfma_f32_16x16x32_f16(av0, bv, acc8[0][nt], 0, 0, 0);
        acc8[1][nt] = __builtin_amdgcn_mfma_f32_16x16x32_f16(av1, bv, acc8[1][nt], 0, 0, 0);
        acc8[2][nt] = __builtin_amdgcn_mfma_f32_16x16x32_f16(av2, bv, acc8[2][nt], 0, 0, 0);
        acc8[3][nt] = __builtin_amdgcn_mfma_f32_16x16x32_f16(av3, bv, acc8[3][nt], 0, 0, 0);
      }
      __builtin_amdgcn_s_setprio(0);
    }
  }
  __syncthreads();   // W + Jl dead; U reusable

  // ---- Reduction: 4 stages x 32 pos; combine 4 ks-partials + bn2 -> P ----
  // stage s: rows 2s,2s+1 -> waves mh==s>>1 write acc8[(s&1)*2 + {0,1}]
  {
    const int ks = wave & 3, mh = wave >> 2;
#pragma unroll
    for (int s = 0; s < 4; ++s) {
      const int smh = s >> 1, sbase = (s & 1) * 2;
      if (mh == smh) {
#pragma unroll
        for (int msl = 0; msl < 2; ++msl)
#pragma unroll
          for (int nt = 0; nt < 8; ++nt)
#pragma unroll
            for (int r = 0; r < 4; ++r)
              Pp[ks * 4096 + (msl * 16 + kgr * 4 + r) * 128 + nt * 16 + nlo]
                = acc8[sbase + msl][nt][r];
      }
      __syncthreads();
#pragma unroll
      for (int q = 0; q < 8; ++q) {
        int idx = q * 512 + tid;                    // 4096 outputs
        int p = idx >> 7, o = idx & 127;
        const float* Pb = Pp + p * 128 + o;
        float sum = Pb[0] + Pb[4096] + Pb[8192] + Pb[12288];
        float v = sum + b_dc[o];
        v = fmaxf(s2[o] * v + t2[o], 0.f);
        P[(s * 32 + p) * 136 + o] = bft(v);
      }
      __syncthreads();
    }
  }

  // ---- conv3 MFMA (bf16, M=128, K=128): wave owns o-tile = wave ----
  float4v acc2[8];
#pragma unroll
  for (int mt = 0; mt < 8; ++mt) acc2[mt] = (float4v)(0.f);
  {
    const u16* bp3 = &w3b[(((size_t)(wave * 4)) * 64 + lane) * 8];
#pragma unroll
    for (int ks3 = 0; ks3 < 4; ++ks3) {
      short8v bv = *(const short8v*)(bp3 + ks3 * 512);
#pragma unroll
      for (int mt = 0; mt < 8; ++mt) {
        short8v a = *(const short8v*)&P[(mt * 16 + nlo) * 136 + ks3 * 32 + kgr * 8];
        acc2[mt] = __builtin_amdgcn_mfma_f32_16x16x32_bf16(a, bv, acc2[mt], 0, 0, 0);
      }
    }
  }

  // bn3 chain -> T2[o][pos129] (overlays dead Pp; P region disjoint)
  {
    int o = wave * 16 + nlo;
    float sa = s3a[o], ta = t3a[o], sb = s3b[o], tb = t3b[o];
#pragma unroll
    for (int mt = 0; mt < 8; ++mt)
#pragma unroll
      for (int r = 0; r < 4; ++r) {
        float v = acc2[mt][r];
        v = fmaxf(sa * v + ta, 0.f);
        v = sb * v + tb;
        T2[o * 129 + mt * 16 + kgr * 4 + r] = v;
      }
  }
  __syncthreads();

  // ---- transpose + ident + relu -> out NCHW fp32 ----
  // thread: o = tid>>2; rows (tid&3)*2 + {0,1}; 16 cols each
  {
    int o = tid >> 2, qd = tid & 3;
#pragma unroll
    for (int rr = 0; rr < 2; ++rr) {
      int row = qd * 2 + rr;
      size_t g = ((size_t)((b * 128 + o) * 128 + h0 + row)) * 128 + w0;
      const float* trow = &T2[o * 129 + row * 16];
      uint4 iv0 = *(const uint4*)&identb[g];
      uint4 iv1 = *(const uint4*)&identb[g + 8];
      u32 iw[8] = {iv0.x, iv0.y, iv0.z, iv0.w, iv1.x, iv1.y, iv1.z, iv1.w};
#pragma unroll
      for (int q = 0; q < 4; ++q) {
        float r0 = trow[q * 4 + 0] + bflo(iw[q * 2]);
        float r1 = trow[q * 4 + 1] + bfhi(iw[q * 2]);
        float r2 = trow[q * 4 + 2] + bflo(iw[q * 2 + 1]);
        float r3 = trow[q * 4 + 3] + bfhi(iw[q * 2 + 1]);
        float4 ov = make_float4(fmaxf(r0, 0.f), fmaxf(r1, 0.f), fmaxf(r2, 0.f), fmaxf(r3, 0.f));
        *(float4*)&out[g + q * 4] = ov;
      }
    }
  }
}

// ---------------------------------------------------------------------------
extern "C" void kernel_launch(void* const* d_in, const int* in_sizes, int n_in,
                              void* d_out, int out_size, void* d_ws, size_t ws_size,
                              hipStream_t stream) {
  const float* x     = (const float*)d_in[0];
  const float* w1    = (const float*)d_in[1];
  const float* s1a   = (const float*)d_in[2];
  const float* t1a   = (const float*)d_in[3];
  const float* s1b   = (const float*)d_in[4];
  const float* t1b   = (const float*)d_in[5];
  const float* w_off = (const float*)d_in[6];
  const float* b_off = (const float*)d_in[7];
  const float* w_dc  = (const float*)d_in[8];
  const float* b_dc  = (const float*)d_in[9];
  const float* s2    = (const float*)d_in[10];
  const float* t2    = (const float*)d_in[11];
  const float* w3    = (const float*)d_in[12];
  const float* s3a   = (const float*)d_in[13];
  const float* t3a   = (const float*)d_in[14];
  const float* s3b   = (const float*)d_in[15];
  const float* t3b   = (const float*)d_in[16];
  const float* w_ds  = (const float*)d_in[17];
  const float* b_ds  = (const float*)d_in[18];
  const float* sd    = (const float*)d_in[19];
  const float* td    = (const float*)d_in[20];

  char* ws = (char*)d_ws;
  u16* wTb    = (u16*)(ws + 0);            //    294,912 B  (f16)
  u16* wB1    = (u16*)(ws + 294912);       //    131,072 B  (bf16)
  u16* w3b    = (u16*)(ws + 425984);       //     32,768 B  (bf16)
  u16* woffb  = (u16*)(ws + 458752);       //     73,728 B  (f16)
  u16* out1   = (u16*)(ws + 532480);       // 16,777,216 B  NHWC f16
  u16* identb = (u16*)(ws + 17309696);     // 16,777,216 B  NCHW bf16

  k_init  <<<1040, 256, 0, stream>>>(w_dc, w1, w_ds, w3, w_off, wTb, wB1, w3b, woffb);
  k_fused1<<<dim3(4, 128, 4), 256, 0, stream>>>(x, wB1, s1a, t1a, s1b, t1b, b_ds, sd, td, out1, identb);
  k_dcn   <<<dim3(8, 16, 4), 512, 0, stream>>>(out1, wTb, w3b, woffb, b_off, b_dc, s2, t2,
                                               s3a, t3a, s3b, t3b, identb, (float*)d_out);
}

// Round 19
// 226.558 us; speedup vs baseline: 1.0286x; 1.0286x over previous
//
#include <hip/hip_runtime.h>
#include <hip/hip_bf16.h>
#include <hip/hip_fp16.h>

#define HW 16384   // 128*128

typedef unsigned short u16;
typedef unsigned int   u32;
typedef __attribute__((ext_vector_type(8))) short short8v;
typedef __attribute__((ext_vector_type(8))) _Float16 half8v;
typedef __attribute__((ext_vector_type(2))) __fp16 fp16x2;
typedef __attribute__((ext_vector_type(4))) float float4v;

__device__ __forceinline__ float b2f(u16 v) { return __uint_as_float((u32)v << 16); }
__device__ __forceinline__ u16 f2bf(float f) {   // RNE (cold paths)
  u32 u = __float_as_uint(f);
  u32 r = (u + 0x7fffu + ((u >> 16) & 1u)) >> 16;
  return (u16)r;
}
__device__ __forceinline__ u16 f2h(float f) {    // f32 -> f16 RNE (cold paths)
  _Float16 h = (_Float16)f;
  return *(u16*)&h;
}
__device__ __forceinline__ float bflo(u32 u) { return __uint_as_float(u << 16); }
__device__ __forceinline__ float bfhi(u32 u) { return __uint_as_float(u & 0xffff0000u); }
// 1-instruction truncating pack: (hi16(b)<<16)|hi16(a)  [v_perm_b32]
__device__ __forceinline__ u32 pkt(float a, float b) {
  return __builtin_amdgcn_perm(__float_as_uint(b), __float_as_uint(a), 0x07060302u);
}
__device__ __forceinline__ u16 bft(float v) { return (u16)(__float_as_uint(v) >> 16); }  // trunc
// f32 pair -> packed f16 pair (v_cvt_pkrtz_f16_f32, 1 op); builtin-native type
__device__ __forceinline__ u32 pkh(float a, float b) {
  union { fp16x2 h; u32 u; } cv;
  cv.h = __builtin_amdgcn_cvt_pkrtz(a, b);
  return cv.u;
}

// ---------------------------------------------------------------------------
// K0: swizzle ALL weights into MFMA-B fragment order.
//  wTb/woffb F16 (DCN path); wB1/w3b BF16.
// ---------------------------------------------------------------------------
__global__ __launch_bounds__(256) void k_init(const float* __restrict__ w_dc,
                                              const float* __restrict__ w1,
                                              const float* __restrict__ w_ds,
                                              const float* __restrict__ w3,
                                              const float* __restrict__ w_off,
                                              u16* __restrict__ wTb, u16* __restrict__ wB1,
                                              u16* __restrict__ w3b, u16* __restrict__ woffb) {
  int idx = blockIdx.x * 256 + threadIdx.x;
  if (idx < 147456) {
    int ntile = idx / 18432, r = idx % 18432;
    int ks = r / 512, r2 = r % 512;
    int lane = r2 / 8, j = r2 % 8;
    int o = ntile * 16 + (lane & 15);
    int k = ks * 32 + ((lane >> 4) * 8) + j;
    int tap = k >> 7, ci = k & 127;
    wTb[idx] = f2h(w_dc[(o * 128 + ci) * 9 + tap]);           // f16
  }
  int i1 = idx - 147456;
  if (i1 >= 0 && i1 < 65536) {
    int ntile = i1 / 4096, r = i1 % 4096;
    int ks = r / 512, r2 = r % 512;
    int lane = r2 / 8, j = r2 % 8;
    int o = ntile * 16 + (lane & 15);
    int c = ks * 32 + ((lane >> 4) * 8) + j;
    float v = (ntile < 8) ? w1[o * 256 + c] : w_ds[(o - 128) * 256 + c];
    wB1[i1] = f2bf(v);                                        // bf16
  }
  int i2 = idx - 212992;
  if (i2 >= 0 && i2 < 16384) {
    int ntile = i2 / 2048, r = i2 % 2048;
    int ks = r / 512, r2 = r % 512;
    int lane = r2 / 8, j = r2 % 8;
    int o = ntile * 16 + (lane & 15);
    int c = ks * 32 + ((lane >> 4) * 8) + j;
    w3b[i2] = f2bf(w3[o * 128 + c]);                          // bf16
  }
  int i3 = idx - 229376;
  if (i3 >= 0 && i3 < 36864) {
    int ntile = i3 / 18432, r = i3 % 18432;
    int ks = r / 512, r2 = r % 512;
    int lane = r2 / 8, j = r2 % 8;
    int oc = ntile * 16 + (lane & 15);
    int k = ks * 32 + ((lane >> 4) * 8) + j;
    int tap = k >> 7, c = k & 127;
    woffb[i3] = (oc < 27) ? f2h(w_off[oc * 1152 + c * 9 + tap]) : (u16)0;   // f16
  }
}

// ---------------------------------------------------------------------------
// K1 v4: fused conv1+downsample MFMA GEMM. M=32, N=256, K=256.
//  (proven; unchanged) grid (4,128,4); block 256 = 4 waves.
// ---------------------------------------------------------------------------
__global__ __launch_bounds__(256) void k_fused1(const float* __restrict__ x,
                                                const u16* __restrict__ wB1,
                                                const float* __restrict__ s1a, const float* __restrict__ t1a,
                                                const float* __restrict__ s1b, const float* __restrict__ t1b,
                                                const float* __restrict__ b_ds,
                                                const float* __restrict__ sd, const float* __restrict__ td,
                                                u16* __restrict__ out1,      // [b][h][w][o]  F16
                                                u16* __restrict__ identb)    // [b][o][h][w]  BF16
{
  __shared__ __align__(16) u16 xA[8704];
  const int tid = threadIdx.x;
  const int wq = blockIdx.x, h = blockIdx.y, b = blockIdx.z;
  const int wave = tid >> 6, lane = tid & 63;

  {
    const float* xb = x + (size_t)b * 256 * HW + h * 128 + wq * 32;
    u32* dst = (u32*)xA;                 // u32 pitch 133 per pos row
    int cp = tid >> 3, wg = tid & 7;
#pragma unroll
    for (int i = 0; i < 4; ++i) {
      int cpair = i * 32 + cp;           // 0..127
      int c0 = cpair * 2;
      float4 va = *(const float4*)&xb[(size_t)c0 * HW + wg * 4];
      float4 vb = *(const float4*)&xb[(size_t)(c0 + 1) * HW + wg * 4];
      int p0 = wg * 4;
      dst[(p0 + 0) * 133 + cpair] = pkt(va.x, vb.x);
      dst[(p0 + 1) * 133 + cpair] = pkt(va.y, vb.y);
      dst[(p0 + 2) * 133 + cpair] = pkt(va.z, vb.z);
      dst[(p0 + 3) * 133 + cpair] = pkt(va.w, vb.w);
    }
  }
  __syncthreads();

  const int nlo = lane & 15, kgr = lane >> 4;
  float4v acc[2][4];
#pragma unroll
  for (int mt = 0; mt < 2; ++mt)
#pragma unroll
    for (int nt = 0; nt < 4; ++nt) acc[mt][nt] = (float4v)(0.f);

  const u16* a0p = &xA[nlo * 266 + kgr * 8];
  const u16* a1p = &xA[(nlo + 16) * 266 + kgr * 8];
  const u16* bp = &wB1[(((size_t)(wave * 4) * 8) * 64 + lane) * 8];

#pragma unroll
  for (int ks = 0; ks < 8; ++ks) {
    short8v a0 = *(const short8v*)(a0p + ks * 32);
    short8v a1 = *(const short8v*)(a1p + ks * 32);
#pragma unroll
    for (int nt = 0; nt < 4; ++nt) {
      short8v bv = *(const short8v*)(bp + nt * 4096 + ks * 512);
      acc[0][nt] = __builtin_amdgcn_mfma_f32_16x16x32_bf16(a0, bv, acc[0][nt], 0, 0, 0);
      acc[1][nt] = __builtin_amdgcn_mfma_f32_16x16x32_bf16(a1, bv, acc[1][nt], 0, 0, 0);
    }
  }
  __syncthreads();   // xA dead; reuse as P1 + T1

  u16* P1 = xA;              // [pos][136]  (f16 out1 tile)
  u16* T1 = xA + 4352;       // [o][34]     (bf16 ident tile)

  const int rbase = kgr * 4;
  if (wave < 2) {
#pragma unroll
    for (int nt = 0; nt < 4; ++nt) {
      int o = (wave * 4 + nt) * 16 + nlo;
      float sa = s1a[o], ta = t1a[o], sb = s1b[o], tb = t1b[o];
#pragma unroll
      for (int mt = 0; mt < 2; ++mt)
#pragma unroll
        for (int r = 0; r < 4; ++r) {
          float v = acc[mt][nt][r];
          v = fmaxf(sa * v + ta, 0.f);
          v = fmaxf(sb * v + tb, 0.f);
          int pos = mt * 16 + rbase + r;
          P1[pos * 136 + o] = f2h(v);                  // F16
        }
    }
  } else {
#pragma unroll
    for (int nt = 0; nt < 4; ++nt) {
      int og = (wave * 4 + nt) * 16 + nlo - 128;
      float sv = sd[og], tv = td[og], bv = b_ds[og];
#pragma unroll
      for (int mt = 0; mt < 2; ++mt)
#pragma unroll
        for (int r = 0; r < 4; ++r) {
          float v = sv * (acc[mt][nt][r] + bv) + tv;
          T1[og * 34 + mt * 16 + rbase + r] = bft(v);  // BF16
        }
    }
  }
  __syncthreads();

  // ---- out1: fully-coalesced uint4 stores (f16 payload) ----
  {
    size_t rowbase = ((size_t)((b * 128 + h) * 128 + wq * 32)) * 128;
#pragma unroll
    for (int i = 0; i < 2; ++i) {
      int s = i * 256 + tid;             // 0..511
      int pos = s >> 4, q = s & 15;
      uint4 v = *(const uint4*)&P1[pos * 136 + q * 8];
      *(uint4*)&out1[rowbase + (size_t)pos * 128 + q * 8] = v;
    }
  }
  // ---- identb: transpose store (bf16, unchanged) ----
  {
    int o = tid >> 1, half = tid & 1;
    const u16* src = &T1[o * 34 + half * 16];
    u32 bb[8];
#pragma unroll
    for (int i = 0; i < 8; ++i) bb[i] = *(const u32*)(src + i * 2);
    size_t g = ((size_t)((b * 128 + o) * 128 + h)) * 128 + wq * 32 + half * 16;
    *(uint4*)&identb[g] = make_uint4(bb[0], bb[1], bb[2], bb[3]);
    *(uint4*)&identb[g + 8] = make_uint4(bb[4], bb[5], bb[6], bb[7]);
  }
}

// ---------------------------------------------------------------------------
// K2: MEGA-FUSED DCNv2, v14 (PROVEN BEST, 79 us): M=64 TILE (4 rows x 16
//  cols): each wave's 72 wTb B-fragment loads feed TWO m-sub-tiles
//  (1 load -> 2 MFMAs); 4 sequential blocks/CU. Measured tile curve:
//  M=32 -> 95us, M=64 -> 79us, M=128 -> 84us (1 blk/CU loses overlap).
//  A2: ntile(2) x mtile(4) per wave, full-K. A3: compute -> uniform
//  barrier -> write Jl (overlays dead offp). Loop B: ks(4) x mh(2) waves,
//  2 m-subs share B-frags, barrier-free, f16 fma_mix blend, tagged
//  LDS-window corner reads. Reduction 4 stages. conv3 M=64. LDS 72.8 KB.
//  grid (8,32,4)=1024; block 512; __launch_bounds__(512,4).
// ---------------------------------------------------------------------------
__global__ __launch_bounds__(512, 4) void k_dcn(const u16* __restrict__ out1,
                                                const u16* __restrict__ wTb,
                                                const u16* __restrict__ w3b,
                                                const u16* __restrict__ woffb,
                                                const float* __restrict__ b_off,
                                                const float* __restrict__ b_dc,
                                                const float* __restrict__ s2, const float* __restrict__ t2,
                                                const float* __restrict__ s3a, const float* __restrict__ t3a,
                                                const float* __restrict__ s3b, const float* __restrict__ t3b,
                                                const u16* __restrict__ identb,
                                                float* __restrict__ out) {
  // LDS map (72,832 B):
  //  W    [0, 54400)      : 200 px x 136 u16 (10x20 window, f16)
  //  reg2 [54400, 72832)  : offp 2048 f32 (A2->A3) THEN Jl 576x8 u32 (A3->B)
  //  reduce (W dead): P [0,17408) 64x136 u16 ; Pp [17408,50176) 8192 f32
  //  conv3/epilogue : P + T2 [17408,50688) 128x65 f32 (Pp dead)
  __shared__ __align__(16) u16 U[36416];

  u16*   W    = U;                                  // pitch 136 u16
  float* offp = (float*)((char*)U + 54400);         // [pos64][oc32]
  u32*   Jl   = (u32*)((char*)U + 54400);           // jobtab (overlays offp)
  float* Pp   = (float*)((char*)U + 17408);         // [ks][p16][o128]
  u16*   P    = U;                                  // [pos64][136]
  float* T2   = (float*)((char*)U + 17408);         // [o][65]

  const int tid = threadIdx.x;
  // XCD-chunked bijective swizzle (1024 blocks, 8 XCDs, 1024%8==0)
  const int flat = blockIdx.x + (blockIdx.y << 3) + (blockIdx.z << 8);
  const int nid = (flat & 7) * 128 + (flat >> 3);
  const int wq = nid & 7, th = (nid >> 3) & 31, b = nid >> 8;
  const int h0 = th * 4, w0 = wq * 16;   // tile rows h0..h0+3, cols w0..w0+15
  const int wave = tid >> 6, lane = tid & 63;
  const int nlo = lane & 15, kgr = lane >> 4;
  const u16* base = out1 + (size_t)b * HW * 128;

  // ---- A1: stage 10x20x128 window rows h0-2..h0+7, cols w0-2..w0+17 ----
  for (int k = tid; k < 3200; k += 512) {           // 200 px * 16 quads
    int pix = k >> 4, q = k & 15;
    int ri = pix / 20, ci = pix % 20;
    int y = h0 - 2 + ri, x = w0 - 2 + ci;
    uint4 g = make_uint4(0u, 0u, 0u, 0u);
    if ((y >= 0) & (y < 128) & (x >= 0) & (x < 128))
      g = *(const uint4*)&base[((size_t)(y * 128 + x)) * 128 + q * 8];
    *(uint4*)&W[pix * 136 + q * 8] = g;
  }
  __syncthreads();

  // ---- A2: offset conv (f16), waves = ntile(2) x mtile(4), FULL K ----
  {
    const int ntile = wave & 1, mt = wave >> 1;     // mt 0..3
    float4v oacc = (float4v)(0.f);
    for (int t = 0; t < 9; ++t) {
      int ty = t / 3, tx = t % 3;
      const u16* bp = &woffb[(((size_t)(ntile * 36 + t * 4)) * 64 + lane) * 8];
      const u16* ap = &W[((mt + ty + 1) * 20 + nlo + tx + 1) * 136 + kgr * 8];
#pragma unroll
      for (int ksl = 0; ksl < 4; ++ksl) {
        half8v bv = *(const half8v*)(bp + ksl * 512);
        half8v a = *(const half8v*)(ap + ksl * 32);
        oacc = __builtin_amdgcn_mfma_f32_16x16x32_f16(a, bv, oacc, 0, 0, 0);
      }
    }
    int oc = ntile * 16 + nlo;
#pragma unroll
    for (int r = 0; r < 4; ++r)
      offp[(mt * 16 + kgr * 4 + r) * 32 + oc] = oacc[r];
  }
  __syncthreads();

  // ---- A3: 576 jobs; compute (reads offp) -> barrier -> write Jl ----
  u32  jc[2][4];
  float jw[2][4];
#pragma unroll
  for (int it = 0; it < 2; ++it) {
    int j = tid + it * 512;
    if (j < 576) {
      int pos = j / 9, tap = j % 9;
      int pr = pos >> 4, pc = pos & 15;
      int hh = h0 + pr, w = w0 + pc;
      float dy  = offp[pos * 32 + tap]      + b_off[tap];
      float dxv = offp[pos * 32 + 9 + tap]  + b_off[9 + tap];
      float sg  = offp[pos * 32 + 18 + tap] + b_off[18 + tap];
      float mk = 1.f / (1.f + __expf(-sg));
      float py = (float)(hh - 1 + tap / 3) + dy;
      float px = (float)(w - 1 + tap % 3) + dxv;
      float fy = floorf(py), fx = floorf(px);
      int y0 = (int)fy, x0 = (int)fx;
      float wy = py - fy, wxf = px - fx;
      bool vy0 = (y0 >= 0) & (y0 < 128), vy1 = (y0 >= -1) & (y0 < 127);
      bool vx0 = (x0 >= 0) & (x0 < 128), vx1 = (x0 >= -1) & (x0 < 127);
      jw[it][0] = (vy0 & vx0) ? (1.f - wy) * (1.f - wxf) * mk : 0.f;
      jw[it][1] = (vy0 & vx1) ? (1.f - wy) * wxf * mk : 0.f;
      jw[it][2] = (vy1 & vx0) ? wy * (1.f - wxf) * mk : 0.f;
      jw[it][3] = (vy1 & vx1) ? wy * wxf * mk : 0.f;
      int y0c = min(max(y0, 0), 127), y1c = min(max(y0 + 1, 0), 127);
      int x0c = min(max(x0, 0), 127), x1c = min(max(x0 + 1, 0), 127);
      auto enc = [&](int yc, int xc) -> u32 {
        int ri = yc - (h0 - 2), ci = xc - (w0 - 2);
        if (((unsigned)ri < 10u) && ((unsigned)ci < 20u))
          return 0x80000000u | (u32)((ri * 20 + ci) * 136);
        return (u32)((yc * 128 + xc) * 128);
      };
      jc[it][0] = enc(y0c, x0c);
      jc[it][1] = enc(y0c, x1c);
      jc[it][2] = enc(y1c, x0c);
      jc[it][3] = enc(y1c, x1c);
    }
  }
  __syncthreads();           // offp reads complete; Jl may overwrite
#pragma unroll
  for (int it = 0; it < 2; ++it) {
    int j = tid + it * 512;
    if (j < 576) {
      u32* jt = &Jl[j * 8];
      jt[0] = jc[it][0]; jt[1] = jc[it][1]; jt[2] = jc[it][2]; jt[3] = jc[it][3];
      ((float*)jt)[4] = jw[it][0]; ((float*)jt)[5] = jw[it][1];
      ((float*)jt)[6] = jw[it][2]; ((float*)jt)[7] = jw[it][3];
    }
  }
  __syncthreads();

  // ---- Loop B: DCN conv (f16), ks(4) x mh(2), 2 m-subs share B-frags ----
  float4v acc8[2][8];
#pragma unroll
  for (int ms = 0; ms < 2; ++ms)
#pragma unroll
    for (int nt = 0; nt < 8; ++nt) acc8[ms][nt] = (float4v)(0.f);
  {
    const int ks = wave & 3, mh = wave >> 2;
    const int ch0 = ks * 32 + kgr * 8;
    const int jrowA = (mh * 32 + nlo) * 9;          // m-sub 0
    const int jrowB = jrowA + 144;                  // m-sub 1 (+16 pos * 9)

    auto BLD = [&](int jidx) -> half8v {
      const u32* jt = &Jl[jidx * 8];
      uint4 co4 = *(const uint4*)jt;
      float4 w4 = *(const float4*)(jt + 4);
      u32 cos[4] = {co4.x, co4.y, co4.z, co4.w};
      float wf[4] = {w4.x, w4.y, w4.z, w4.w};
      float alo[4] = {0.f, 0.f, 0.f, 0.f};
      float ahi[4] = {0.f, 0.f, 0.f, 0.f};
#pragma unroll
      for (int c = 0; c < 4; ++c) {
        u32 co = cos[c];
        short8v cv;
        if (co & 0x80000000u)
          cv = *(const short8v*)&W[(co & 0x7fffffffu) + ch0];   // LDS pipe
        else
          cv = *(const short8v*)(base + co + ch0);              // rare global
        union { short8v s; _Float16 h[8]; } cc; cc.s = cv;
        float wk = wf[c];
#pragma unroll
        for (int p = 0; p < 4; ++p) {
          alo[p] = fmaf(wk, (float)cc.h[2 * p],     alo[p]);
          ahi[p] = fmaf(wk, (float)cc.h[2 * p + 1], ahi[p]);
        }
      }
      union { u32 u[4]; half8v s; } av;
#pragma unroll
      for (int p = 0; p < 4; ++p) av.u[p] = pkh(alo[p], ahi[p]);
      return av.s;
    };

#pragma unroll
    for (int t = 0; t < 9; ++t) {
      half8v av0 = BLD(jrowA + t);
      half8v av1 = BLD(jrowB + t);
      const u16* bb = &wTb[(((size_t)(t * 4 + ks)) * 64 + lane) * 8];
      __builtin_amdgcn_s_setprio(1);
#pragma unroll
      for (int nt = 0; nt < 8; ++nt) {
        half8v bv = *(const half8v*)(bb + (size_t)nt * 18432);
        acc8[0][nt] = __builtin_amdgcn_mfma_f32_16x16x32_f16(av0, bv, acc8[0][nt], 0, 0, 0);
        acc8[1][nt] = __builtin_amdgcn_mfma_f32_16x16x32_f16(av1, bv, acc8[1][nt], 0, 0, 0);
      }
      __builtin_amdgcn_s_setprio(0);
    }
  }
  __syncthreads();   // W + Jl dead; U reusable

  // ---- Reduction: 4 stages (mh,msub); combine 4 ks-partials + bn2 -> P ----
  {
    const int ks = wave & 3, mh = wave >> 2;
#pragma unroll
    for (int s = 0; s < 4; ++s) {
      const int smh = s >> 1, sms = s & 1;
      if (mh == smh) {
#pragma unroll
        for (int nt = 0; nt < 8; ++nt)
#pragma unroll
          for (int r = 0; r < 4; ++r)
            Pp[ks * 2048 + (kgr * 4 + r) * 128 + nt * 16 + nlo] = acc8[sms][nt][r];
      }
      __syncthreads();
#pragma unroll
      for (int q = 0; q < 4; ++q) {
        int idx = q * 512 + tid;                    // 2048 outputs
        int p16 = idx >> 7, o = idx & 127;
        const float* Pb = Pp + p16 * 128 + o;
        float sum = Pb[0] + Pb[2048] + Pb[4096] + Pb[6144];
        float v = sum + b_dc[o];
        v = fmaxf(s2[o] * v + t2[o], 0.f);
        P[(s * 16 + p16) * 136 + o] = bft(v);
      }
      __syncthreads();
    }
  }

  // ---- conv3 MFMA (bf16, M=64, K=128): wave owns o-tile = wave ----
  float4v acc2[4];
#pragma unroll
  for (int mt = 0; mt < 4; ++mt) acc2[mt] = (float4v)(0.f);
  {
    const u16* bp3 = &w3b[(((size_t)(wave * 4)) * 64 + lane) * 8];
#pragma unroll
    for (int ks3 = 0; ks3 < 4; ++ks3) {
      short8v bv = *(const short8v*)(bp3 + ks3 * 512);
#pragma unroll
      for (int mt = 0; mt < 4; ++mt) {
        short8v a = *(const short8v*)&P[(mt * 16 + nlo) * 136 + ks3 * 32 + kgr * 8];
        acc2[mt] = __builtin_amdgcn_mfma_f32_16x16x32_bf16(a, bv, acc2[mt], 0, 0, 0);
      }
    }
  }

  // bn3 chain -> T2[o][pos65] (overlays dead Pp; P region disjoint)
  {
    int o = wave * 16 + nlo;
    float sa = s3a[o], ta = t3a[o], sb = s3b[o], tb = t3b[o];
#pragma unroll
    for (int mt = 0; mt < 4; ++mt)
#pragma unroll
      for (int r = 0; r < 4; ++r) {
        float v = acc2[mt][r];
        v = fmaxf(sa * v + ta, 0.f);
        v = sb * v + tb;
        T2[o * 65 + mt * 16 + kgr * 4 + r] = v;
      }
  }
  __syncthreads();

  // ---- transpose + ident + relu -> out NCHW fp32 ----
  // thread: o = tid>>2, row h0+qd, 16 cols
  {
    int o = tid >> 2, qd = tid & 3;
    size_t g = ((size_t)((b * 128 + o) * 128 + h0 + qd)) * 128 + w0;
    const float* trow = &T2[o * 65 + qd * 16];
    uint4 iv0 = *(const uint4*)&identb[g];
    uint4 iv1 = *(const uint4*)&identb[g + 8];
    u32 iw[8] = {iv0.x, iv0.y, iv0.z, iv0.w, iv1.x, iv1.y, iv1.z, iv1.w};
#pragma unroll
    for (int q = 0; q < 4; ++q) {
      float r0 = trow[q * 4 + 0] + bflo(iw[q * 2]);
      float r1 = trow[q * 4 + 1] + bfhi(iw[q * 2]);
      float r2 = trow[q * 4 + 2] + bflo(iw[q * 2 + 1]);
      float r3 = trow[q * 4 + 3] + bfhi(iw[q * 2 + 1]);
      float4 ov = make_float4(fmaxf(r0, 0.f), fmaxf(r1, 0.f), fmaxf(r2, 0.f), fmaxf(r3, 0.f));
      *(float4*)&out[g + q * 4] = ov;
    }
  }
}

// ---------------------------------------------------------------------------
extern "C" void kernel_launch(void* const* d_in, const int* in_sizes, int n_in,
                              void* d_out, int out_size, void* d_ws, size_t ws_size,
                              hipStream_t stream) {
  const float* x     = (const float*)d_in[0];
  const float* w1    = (const float*)d_in[1];
  const float* s1a   = (const float*)d_in[2];
  const float* t1a   = (const float*)d_in[3];
  const float* s1b   = (const float*)d_in[4];
  const float* t1b   = (const float*)d_in[5];
  const float* w_off = (const float*)d_in[6];
  const float* b_off = (const float*)d_in[7];
  const float* w_dc  = (const float*)d_in[8];
  const float* b_dc  = (const float*)d_in[9];
  const float* s2    = (const float*)d_in[10];
  const float* t2    = (const float*)d_in[11];
  const float* w3    = (const float*)d_in[12];
  const float* s3a   = (const float*)d_in[13];
  const float* t3a   = (const float*)d_in[14];
  const float* s3b   = (const float*)d_in[15];
  const float* t3b   = (const float*)d_in[16];
  const float* w_ds  = (const float*)d_in[17];
  const float* b_ds  = (const float*)d_in[18];
  const float* sd    = (const float*)d_in[19];
  const float* td    = (const float*)d_in[20];

  char* ws = (char*)d_ws;
  u16* wTb    = (u16*)(ws + 0);            //    294,912 B  (f16)
  u16* wB1    = (u16*)(ws + 294912);       //    131,072 B  (bf16)
  u16* w3b    = (u16*)(ws + 425984);       //     32,768 B  (bf16)
  u16* woffb  = (u16*)(ws + 458752);       //     73,728 B  (f16)
  u16* out1   = (u16*)(ws + 532480);       // 16,777,216 B  NHWC f16
  u16* identb = (u16*)(ws + 17309696);     // 16,777,216 B  NCHW bf16

  k_init  <<<1040, 256, 0, stream>>>(w_dc, w1, w_ds, w3, w_off, wTb, wB1, w3b, woffb);
  k_fused1<<<dim3(4, 128, 4), 256, 0, stream>>>(x, wB1, s1a, t1a, s1b, t1b, b_ds, sd, td, out1, identb);
  k_dcn   <<<dim3(8, 32, 4), 512, 0, stream>>>(out1, wTb, w3b, woffb, b_off, b_dc, s2, t2,
                                               s3a, t3a, s3b, t3b, identb, (float*)d_out);
}